// Round 1
// baseline (602.481 us; speedup 1.0000x reference)
//
#include <hip/hip_runtime.h>
#include <stdint.h>

typedef int v4i  __attribute__((ext_vector_type(4)));
typedef int v16i __attribute__((ext_vector_type(16)));

// ---------------------------------------------------------------------------
// async global->LDS, 16 bytes per lane. LDS dest is wave-uniform base +
// lane*16 (HW takes readfirstlane of the provided pointer), so each thread
// passes its own &lds[t*16] and lane 0 of each wave carries the wave base.
// ---------------------------------------------------------------------------
__device__ __forceinline__ void async_load16(const void* g, void* l) {
    auto gp = (const __attribute__((address_space(1))) unsigned int*)(uintptr_t)g;
    auto lp = (__attribute__((address_space(3))) unsigned int*)(unsigned int)(uintptr_t)l;
    __builtin_amdgcn_global_load_lds(gp, lp, 16, 0, 0);
}

// ---------------------------------------------------------------------------
// ws scalar slots: [0..1] uint absmax bits (x, w); floats at byte 8:
// sc[0]=s_x, sc[1]=s_w, sc[2]=1/(s_x*s_w)
// ---------------------------------------------------------------------------
__global__ void k_init(unsigned* bits) {
    if (threadIdx.x < 2) bits[threadIdx.x] = 0u;
}

__global__ void k_absmax(const float4* __restrict__ in, int n4,
                         unsigned* __restrict__ out_bits) {
    float m = 0.0f;
    int stride = gridDim.x * blockDim.x;
    for (int i = blockIdx.x * blockDim.x + threadIdx.x; i < n4; i += stride) {
        float4 v = in[i];
        m = fmaxf(m, fmaxf(fmaxf(fabsf(v.x), fabsf(v.y)),
                           fmaxf(fabsf(v.z), fabsf(v.w))));
    }
    #pragma unroll
    for (int off = 32; off > 0; off >>= 1)
        m = fmaxf(m, __shfl_down(m, off, 64));
    __shared__ float red[4];
    int lane = threadIdx.x & 63, wv = threadIdx.x >> 6;
    if (lane == 0) red[wv] = m;
    __syncthreads();
    if (threadIdx.x == 0) {
        m = fmaxf(fmaxf(red[0], red[1]), fmaxf(red[2], red[3]));
        // |x| >= 0: IEEE bit pattern of non-negative floats is order-preserving
        atomicMax(out_bits, __float_as_uint(m));
    }
}

__global__ void k_scales(const unsigned* __restrict__ bits, float* __restrict__ sc) {
    float s[2];
    for (int i = 0; i < 2; ++i) {
        float m = __uint_as_float(bits[i]);
        int ex = 0;
        if (m > 0.0f) {
            int e;
            float f = frexpf(m, &e);      // m = f * 2^e, f in [0.5, 1)
            ex = (f == 0.5f) ? (e - 1) : e;  // exact ceil(log2(m))
        }
        s[i] = ldexpf(1.0f, 7 - ex);       // 2^(8 - ex - 1)
    }
    sc[0] = s[0];
    sc[1] = s[1];
    sc[2] = 1.0f / (s[0] * s[1]);          // powers of two: exact
}

// round-half-even (rintf) == jnp.round; clip AFTER round, matching reference
__global__ void k_quant(const float4* __restrict__ in, int* __restrict__ out,
                        const float* __restrict__ scp, int n4) {
    float s = scp[0];
    int stride = gridDim.x * blockDim.x;
    for (int i = blockIdx.x * blockDim.x + threadIdx.x; i < n4; i += stride) {
        float4 v = in[i];
        int qa = (int)rintf(v.x * s); qa = qa > 127 ? 127 : (qa < -127 ? -127 : qa);
        int qb = (int)rintf(v.y * s); qb = qb > 127 ? 127 : (qb < -127 ? -127 : qb);
        int qc = (int)rintf(v.z * s); qc = qc > 127 ? 127 : (qc < -127 ? -127 : qc);
        int qd = (int)rintf(v.w * s); qd = qd > 127 ? 127 : (qd < -127 ? -127 : qd);
        out[i] = (qa & 0xff) | ((qb & 0xff) << 8) | ((qc & 0xff) << 16) | (qd << 24);
    }
}

// ---------------------------------------------------------------------------
// int8 NT GEMM: C[m][n] = sum_k A[m][k] * B[n][k], both K-major.
// 128x128 tile, BK=64, 256 threads = 4 waves (2x2), each wave: 2x2 of
// v_mfma_i32_32x32x32_i8 (64x64 per wave). m97 2-barrier structure with
// width-16 global_load_lds staging.
// Fragment layouts (32x32, per verified bf16 32x32 mapping extended to i8):
//   A: lane holds A[m = lane&31][k = (lane>>5)*16 + j], j=0..15 contiguous
//   B: lane holds B[n = lane&31][k = (lane>>5)*16 + j]   (NT: B given K-major)
//   C/D: col = lane&31, row = (reg&3) + 8*(reg>>2) + 4*(lane>>5)
// ---------------------------------------------------------------------------
__global__ __launch_bounds__(256) void k_gemm(const signed char* __restrict__ A,
                                              const signed char* __restrict__ B,
                                              float* __restrict__ out,
                                              const float* __restrict__ scp) {
    __shared__ __align__(16) signed char As[128 * 64];
    __shared__ __align__(16) signed char Bs[128 * 64];
    const int tid  = threadIdx.x;
    const int lane = tid & 63;
    const int wave = tid >> 6;
    const int wm   = wave & 1;
    const int wn   = wave >> 1;
    const int m0   = blockIdx.y * 128;
    const int n0   = blockIdx.x * 128;
    const int l31  = lane & 31;
    const int lhi  = lane >> 5;

    v16i acc[2][2];
    #pragma unroll
    for (int a = 0; a < 2; ++a)
        #pragma unroll
        for (int b = 0; b < 2; ++b)
            #pragma unroll
            for (int i = 0; i < 16; ++i) acc[a][b][i] = 0;

    // staging: thread t covers tile row t>>2 (first half) / 64 + t>>2 (second),
    // 16B chunk (t&3)*16 -> LDS byte t*16 (+4096), row-major [128][64].
    const signed char* gA = A + (size_t)(m0 + (tid >> 2)) * 1024 + (tid & 3) * 16;
    const signed char* gB = B + (size_t)(n0 + (tid >> 2)) * 1024 + (tid & 3) * 16;
    signed char* lA = As + tid * 16;
    signed char* lB = Bs + tid * 16;

    for (int k0 = 0; k0 < 1024; k0 += 64) {
        async_load16(gA + k0,             lA);
        async_load16(gA + k0 + 64 * 1024, lA + 4096);
        async_load16(gB + k0,             lB);
        async_load16(gB + k0 + 64 * 1024, lB + 4096);
        __syncthreads();
        #pragma unroll
        for (int kc = 0; kc < 2; ++kc) {
            const int kb = kc * 32 + lhi * 16;
            v4i a0 = *(const v4i*)(As + (wm * 64 +      l31) * 64 + kb);
            v4i a1 = *(const v4i*)(As + (wm * 64 + 32 + l31) * 64 + kb);
            v4i b0 = *(const v4i*)(Bs + (wn * 64 +      l31) * 64 + kb);
            v4i b1 = *(const v4i*)(Bs + (wn * 64 + 32 + l31) * 64 + kb);
            acc[0][0] = __builtin_amdgcn_mfma_i32_32x32x32_i8(a0, b0, acc[0][0], 0, 0, 0);
            acc[0][1] = __builtin_amdgcn_mfma_i32_32x32x32_i8(a0, b1, acc[0][1], 0, 0, 0);
            acc[1][0] = __builtin_amdgcn_mfma_i32_32x32x32_i8(a1, b0, acc[1][0], 0, 0, 0);
            acc[1][1] = __builtin_amdgcn_mfma_i32_32x32x32_i8(a1, b1, acc[1][1], 0, 0, 0);
        }
        __syncthreads();
    }

    const float inv = scp[0];
    #pragma unroll
    for (int tm = 0; tm < 2; ++tm)
        #pragma unroll
        for (int tn = 0; tn < 2; ++tn)
            #pragma unroll
            for (int r = 0; r < 16; ++r) {
                int row = m0 + wm * 64 + tm * 32 + (r & 3) + 8 * (r >> 2) + 4 * lhi;
                int col = n0 + wn * 64 + tn * 32 + l31;
                out[(size_t)row * 1024 + col] = (float)acc[tm][tn][r] * inv;
            }
}

// ---------------------------------------------------------------------------
extern "C" void kernel_launch(void* const* d_in, const int* in_sizes, int n_in,
                              void* d_out, int out_size, void* d_ws, size_t ws_size,
                              hipStream_t stream) {
    const float* x = (const float*)d_in[0];   // [65536,1024]
    const float* w = (const float*)d_in[1];   // [1024,1024]
    // d_in[2] (bias) is unused by the reference
    float* out = (float*)d_out;               // [65536,1024] fp32

    const int NX = 65536 * 1024;              // x elements
    const int NW = 1024 * 1024;               // w elements

    char* ws = (char*)d_ws;
    unsigned* bits = (unsigned*)ws;           // 2 uints
    float* sc = (float*)(ws + 8);             // 3 floats
    signed char* qx = (signed char*)(ws + 256);
    signed char* qw = qx + (size_t)NX;        // + 64 MB

    k_init<<<1, 64, 0, stream>>>(bits);
    k_absmax<<<2048, 256, 0, stream>>>((const float4*)x, NX / 4, bits + 0);
    k_absmax<<<256, 256, 0, stream>>>((const float4*)w, NW / 4, bits + 1);
    k_scales<<<1, 1, 0, stream>>>(bits, sc);
    k_quant<<<4096, 256, 0, stream>>>((const float4*)x, (int*)qx, sc + 0, NX / 4);
    k_quant<<<512, 256, 0, stream>>>((const float4*)w, (int*)qw, sc + 1, NW / 4);

    dim3 grid(1024 / 128, 65536 / 128);       // (8, 512)
    k_gemm<<<grid, 256, 0, stream>>>(qx, qw, out, sc + 2);
}